// Round 12
// baseline (50994.635 us; speedup 1.0000x reference)
//
#include <hip/hip_runtime.h>
#include <hip/hip_bf16.h>
#include <stdint.h>
#include <stddef.h>

using bf16_t = __hip_bfloat16;
typedef __attribute__((ext_vector_type(8))) short short8;
typedef __attribute__((ext_vector_type(4))) float f32x4;

constexpr int BATCH = 4096, DATA = 512, HID = 1024;
constexpr int R    = 16;            // batch rows per block
constexpr int NBLK = BATCH / R;     // 256 blocks, 1/CU (113KB LDS forces it)
constexpr int ZP   = 520;           // z strip stride (bf16): 1040B rows, 16B-aligned
constexpr int HP   = 1032;          // h strip stride (bf16): 2064B rows, 16B-aligned
constexpr int YP   = 516;           // y strip stride (f32):  2064B rows, 16B-aligned

// ---------------------------------------------------------------------------
// quarter GEMM: 16 rows x 64 cols output, K-loop over packed weights.
// A: LDS strip (row-major, stride AP elems). B: fragment-packed weights
// (r11 format, validated): frag(ntile,kt,kk) at ((ntile*(K/64)+kt)*2+kk)*512
// + lane*8  -> wave-uniform base + lane*16B = one coalesced dwordx4/frag.
// Register ping-pong prefetch (static names); compiler inserts vmcnt waits
// for B-register uses (plain loads, no gload_lds).
// ---------------------------------------------------------------------------
template<int AP, int K>
__device__ __forceinline__ void quarter_gemm(
    const bf16_t* __restrict__ As, const bf16_t* __restrict__ Bq,
    int lane, f32x4 acc[4])
{
  constexpr int ntk = K >> 6;                       // 8 or 16 (even)
  const bf16_t* arow = As + (lane & 15) * AP + (lane >> 4) * 8;

  auto loadB = [&](short8* d, int kt) {
#pragma unroll
    for (int ni = 0; ni < 4; ++ni)
#pragma unroll
      for (int kk = 0; kk < 2; ++kk)
        d[ni * 2 + kk] = *(const short8*)
            (Bq + ((size_t)(ni * ntk + kt) * 2 + kk) * 512);
  };
  auto comp = [&](const short8* b, int kt) {
#pragma unroll
    for (int kk = 0; kk < 2; ++kk) {
      short8 af = *(const short8*)(arow + kt * 64 + kk * 32);
#pragma unroll
      for (int ni = 0; ni < 4; ++ni)
        acc[ni] = __builtin_amdgcn_mfma_f32_16x16x32_bf16(
            af, b[ni * 2 + kk], acc[ni], 0, 0, 0);
    }
  };

  short8 bA[8], bB[8];
  loadB(bA, 0);
  for (int kt = 0; kt < ntk; kt += 2) {
    loadB(bB, kt + 1);
    comp(bA, kt);
    if (kt + 2 < ntk) loadB(bA, kt + 2);
    comp(bB, kt + 1);
  }
}

// hidden layer: Os[16 x 1024] = relu(As @ W^T + bias), wave w covers cols
// [w*256, w*256+256) as 4 quarters of 4 subtiles.
template<int AP, int K>
__device__ __forceinline__ void mlp_layer(
    const bf16_t* __restrict__ As, bf16_t* __restrict__ Os,
    const bf16_t* __restrict__ Wp, const float* __restrict__ bias,
    int wid, int lane)
{
  constexpr int ntk = K >> 6;
  const int ro = lane & 15, rq = lane >> 4;
#pragma unroll 1
  for (int q = 0; q < 4; ++q) {
    f32x4 acc[4] = {};
    const int ntile0 = wid * 16 + q * 4;
    const bf16_t* Bq = Wp + (size_t)ntile0 * ntk * 2 * 512 + (size_t)lane * 8;
    quarter_gemm<AP, K>(As, Bq, lane, acc);
#pragma unroll
    for (int ni = 0; ni < 4; ++ni) {
      const int col = (ntile0 + ni) * 16 + ro;
      const float bv = bias[col];
#pragma unroll
      for (int r = 0; r < 4; ++r)
        Os[(rq * 4 + r) * HP + col] =
            __float2bfloat16(fmaxf(acc[ni][r] + bv, 0.f));
    }
  }
}

// ---------------------------------------------------------------------------
extern "C" __global__ void __launch_bounds__(256, 1) ode_fused(
    const float* __restrict__ x,
    const float* __restrict__ b1, const float* __restrict__ b2,
    const float* __restrict__ b3,
    const bf16_t* __restrict__ W1p, const bf16_t* __restrict__ W2p,
    const bf16_t* __restrict__ W3p,
    bf16_t* __restrict__ k1g, bf16_t* __restrict__ k2g,
    bf16_t* __restrict__ k3g, bf16_t* __restrict__ k4g,
    bf16_t* __restrict__ k5g,
    float* __restrict__ outg)
{
  __shared__ __align__(16) bf16_t zs [R * ZP];   // z / y_bf16 strip
  __shared__ __align__(16) bf16_t h1s[R * HP];
  __shared__ __align__(16) bf16_t h2s[R * HP];
  __shared__ __align__(16) float  ys [R * YP];   // fp32 integration state

  const int blk = blockIdx.x, t = threadIdx.x;
  const int lane = t & 63, wid = t >> 6;

  // init strips from x (coalesced float4)
  for (int i = t * 4; i < R * DATA; i += 256 * 4) {
    float4 v = *(const float4*)(x + (size_t)blk * R * DATA + i);
    const int row = i >> 9, col = i & 511;
    *(float4*)&ys[row * YP + col] = v;
    bf16_t o[4] = {__float2bfloat16(v.x), __float2bfloat16(v.y),
                   __float2bfloat16(v.z), __float2bfloat16(v.w)};
    *(uint64_t*)&zs[row * ZP + col] = *(uint64_t*)o;
  }
  __syncthreads();

  constexpr double hh = 1.0 / 64.0;
  constexpr float hA21 = (float)(hh * (1.0/5.0));
  constexpr float hA31 = (float)(hh * (3.0/40.0)),   hA32 = (float)(hh * (9.0/40.0));
  constexpr float hA41 = (float)(hh * (44.0/45.0)),  hA42 = (float)(hh * (-56.0/15.0)),
                  hA43 = (float)(hh * (32.0/9.0));
  constexpr float hA51 = (float)(hh * (19372.0/6561.0)), hA52 = (float)(hh * (-25360.0/2187.0)),
                  hA53 = (float)(hh * (64448.0/6561.0)), hA54 = (float)(hh * (-212.0/729.0));
  constexpr float hA61 = (float)(hh * (9017.0/3168.0)),  hA62 = (float)(hh * (-355.0/33.0)),
                  hA63 = (float)(hh * (46732.0/5247.0)), hA64 = (float)(hh * (49.0/176.0)),
                  hA65 = (float)(hh * (-5103.0/18656.0));
  constexpr float hB1 = (float)(hh * (35.0/384.0)),  hB3 = (float)(hh * (500.0/1113.0)),
                  hB4 = (float)(hh * (125.0/192.0)), hB5 = (float)(hh * (-2187.0/6784.0)),
                  hB6 = (float)(hh * (11.0/84.0));

  const int ro = lane & 15, rq = lane >> 4;
  constexpr int ntk3 = HID >> 6;

  for (int step = 0; step < 64; ++step) {
    for (int s = 0; s < 6; ++s) {
      // G1: h1 = relu(z @ W1^T + b1)    (A = zs, K=512)
      mlp_layer<ZP, DATA>(zs, h1s, W1p, b1, wid, lane);
      __syncthreads();
      // G2: h2 = relu(h1 @ W2^T + b2)   (K=1024)
      mlp_layer<HP, HID>(h1s, h2s, W2p, b2, wid, lane);
      __syncthreads();

      // G3 + RK combine (N=512: wave covers 128 cols = 2 quarters)
      const bf16_t *p0 = nullptr, *p1 = nullptr, *p2 = nullptr, *p3 = nullptr;
      float c0 = 0.f, c1 = 0.f, c2 = 0.f, c3 = 0.f, ccur;
      bf16_t* kd = nullptr;
      switch (s) {
        case 0: ccur = hA21; kd = k1g; break;
        case 1: ccur = hA32; kd = k2g; p0 = k1g; c0 = hA31; break;
        case 2: ccur = hA43; kd = k3g; p0 = k1g; c0 = hA41; p1 = k2g; c1 = hA42; break;
        case 3: ccur = hA54; kd = k4g; p0 = k1g; c0 = hA51; p1 = k2g; c1 = hA52;
                p2 = k3g; c2 = hA53; break;
        case 4: ccur = hA65; kd = k5g; p0 = k1g; c0 = hA61; p1 = k2g; c1 = hA62;
                p2 = k3g; c2 = hA63; p3 = k4g; c3 = hA64; break;
        default: ccur = hB6; p0 = k1g; c0 = hB1; p1 = k3g; c1 = hB3;
                 p2 = k4g; c2 = hB4; p3 = k5g; c3 = hB5; break;
      }
      const bool finy = (s == 5);
      const bool wout = finy && (step == 63);

#pragma unroll 1
      for (int q = 0; q < 2; ++q) {
        f32x4 acc[4] = {};
        const int ntile0 = wid * 8 + q * 4;
        const bf16_t* Bq = W3p + (size_t)ntile0 * ntk3 * 2 * 512
                               + (size_t)lane * 8;
        quarter_gemm<HP, HID>(h2s, Bq, lane, acc);
#pragma unroll
        for (int ni = 0; ni < 4; ++ni) {
          const int col = (ntile0 + ni) * 16 + ro;
          const float bv = b3[col];
#pragma unroll
          for (int r = 0; r < 4; ++r) {
            const int row  = rq * 4 + r;
            const size_t g = (size_t)(blk * R + row) * DATA + col;
            const float v  = acc[ni][r] + bv;
            if (kd) kd[g] = __float2bfloat16(v);
            float z = ys[row * YP + col] + ccur * v;
            if (p0) z += c0 * __bfloat162float(p0[g]);
            if (p1) z += c1 * __bfloat162float(p1[g]);
            if (p2) z += c2 * __bfloat162float(p2[g]);
            if (p3) z += c3 * __bfloat162float(p3[g]);
            if (finy) ys[row * YP + col] = z;
            if (wout) outg[g] = z;
            zs[row * ZP + col] = __float2bfloat16(z);
          }
        }
      }
      __syncthreads();
    }
  }
}

// ---------------------------------------------------------------------------
// weight pack (r11 format, validated): chunk c holds frag slot c:
// lane=c&63; kk=(c>>6)&1; kt=(c>>7)%ntk; ntile=c/(ntk*128);
// src = W[ntile*16+(lane&15)][kt*64+kk*32+(lane>>4)*8 .. +8]
// ---------------------------------------------------------------------------
__device__ __forceinline__ void pack_w(const float* __restrict__ W,
                                       bf16_t* __restrict__ Wp,
                                       int N, int K, int gt, int gs)
{
  const int nchunk = (N * K) / 8;
  const int ktn = K >> 6;
  for (int c = gt; c < nchunk; c += gs) {
    int lane  = c & 63;
    int kk    = (c >> 6) & 1;
    int kt    = (c >> 7) % ktn;
    int ntile = c / (ktn * 128);
    const float* src = W + (size_t)(ntile * 16 + (lane & 15)) * K
                         + kt * 64 + kk * 32 + (lane >> 4) * 8;
    bf16_t o[8];
#pragma unroll
    for (int j = 0; j < 8; ++j) o[j] = __float2bfloat16(src[j]);
    *(short8*)(Wp + (size_t)c * 8) = *(short8*)o;
  }
}

extern "C" __global__ void pack_all(const float* __restrict__ W1,
                                    const float* __restrict__ W2,
                                    const float* __restrict__ W3,
                                    bf16_t* __restrict__ W1p,
                                    bf16_t* __restrict__ W2p,
                                    bf16_t* __restrict__ W3p)
{
  const int gt = blockIdx.x * blockDim.x + threadIdx.x;
  const int gs = gridDim.x * blockDim.x;
  pack_w(W1, W1p, HID, DATA, gt, gs);
  pack_w(W2, W2p, HID, HID, gt, gs);
  pack_w(W3, W3p, DATA, HID, gt, gs);
}

// ---------------------------------------------------------------------------
extern "C" void kernel_launch(void* const* d_in, const int* in_sizes, int n_in,
                              void* d_out, int out_size, void* d_ws, size_t ws_size,
                              hipStream_t stream)
{
  const float* x  = (const float*)d_in[0];
  const float* W1 = (const float*)d_in[1];
  const float* b1 = (const float*)d_in[2];
  const float* W2 = (const float*)d_in[3];
  const float* b2 = (const float*)d_in[4];
  const float* W3 = (const float*)d_in[5];
  const float* b3 = (const float*)d_in[6];

  char* ws = (char*)d_ws;
  size_t off = 0;
  auto alloc = [&](size_t bytes) -> void* {
    off = (off + 255) & ~(size_t)255;
    void* p = ws + off;
    off += bytes;
    return p;
  };
  const size_t nyd = (size_t)BATCH * DATA;

  bf16_t* k1g = (bf16_t*)alloc(nyd * 2);
  bf16_t* k2g = (bf16_t*)alloc(nyd * 2);
  bf16_t* k3g = (bf16_t*)alloc(nyd * 2);
  bf16_t* k4g = (bf16_t*)alloc(nyd * 2);
  bf16_t* k5g = (bf16_t*)alloc(nyd * 2);
  bf16_t* W1p = (bf16_t*)alloc((size_t)HID * DATA * 2);
  bf16_t* W2p = (bf16_t*)alloc((size_t)HID * HID * 2);
  bf16_t* W3p = (bf16_t*)alloc((size_t)DATA * HID * 2);

  pack_all<<<2048, 256, 0, stream>>>(W1, W2, W3, W1p, W2p, W3p);
  ode_fused<<<NBLK, 256, 0, stream>>>(x, b1, b2, b3, W1p, W2p, W3p,
                                      k1g, k2g, k3g, k4g, k5g,
                                      (float*)d_out);
}

// Round 13
// 22700.471 us; speedup vs baseline: 2.2464x; 2.2464x over previous
//
#include <hip/hip_runtime.h>
#include <hip/hip_bf16.h>
#include <stdint.h>
#include <stddef.h>

using bf16_t = __hip_bfloat16;
typedef __attribute__((ext_vector_type(8))) short short8;
typedef __attribute__((ext_vector_type(4))) float f32x4;

// async global->LDS 16B copy (wave-uniform LDS base + lane*16 dest pattern)
__device__ __forceinline__ void gload_lds16(void* lds, const void* g) {
  __builtin_amdgcn_global_load_lds(
      (const __attribute__((address_space(1))) unsigned int*)g,
      (__attribute__((address_space(3))) unsigned int*)lds,
      16, 0, 0);
}

// ---------------------------------------------------------------------------
// GEMM  C[m][n] = sum_k A[m][k] * B[n][k]   (A: MxK bf16, B: NxK bf16)
// BM=BN=64, BK=64. 4 waves (2x2), wave tile 32x32, 256 threads.
// 4-buffer LDS ring (64 KB -> 2 blocks/CU), prefetch depth 2, CORRECT
// counted-vmcnt ladder (T4): at iter tt wait vmcnt(8) -> retires tile tt's
// 4 loads, keeps tiles tt+1/tt+2 (8 loads) in flight. 1 barrier per K-step:
//   [wait vmcnt(8)] [barrier] [stage tt+3 -> buf (tt+3)&3] [setprio MFMA]
// Safety: buf (tt+3)&3 == buf (tt-1)&3, whose readers all passed the
// PREVIOUS iteration's barrier before this one.
// LDS 16B-chunk XOR swizzle (slot s^(row&7)) via pre-swizzled global source.
// 1-D grid, XCD-bijective swizzle (T1): nwg % 8 == 0.
// MODE 0: obf=bf16(relu(acc+bias)); MODE 1: k-store + RK combine;
// MODE 2: RK combine + fp32 y write.
// ---------------------------------------------------------------------------
template<int MODE>
__device__ __forceinline__ void gemm_core(
    const bf16_t* __restrict__ A, const bf16_t* __restrict__ B,
    const float* __restrict__ bias,
    bf16_t* __restrict__ obf,
    bf16_t* __restrict__ kout,
    float* __restrict__ yf_out,
    const float* __restrict__ y_in,
    const bf16_t* __restrict__ kp0, const bf16_t* __restrict__ kp1,
    const bf16_t* __restrict__ kp2, const bf16_t* __restrict__ kp3,
    float c0, float c1, float c2, float c3, float ccur,
    int M, int N, int K, int lgx)
{
  __shared__ __align__(16) bf16_t As[4][64 * 64];
  __shared__ __align__(16) bf16_t Bs[4][64 * 64];

  const int t    = threadIdx.x;
  const int lane = t & 63;
  const int wid  = t >> 6;
  const int wm   = wid >> 1;   // 0..1
  const int wn   = wid & 1;    // 0..1

  const int nwg = gridDim.x, bid = blockIdx.x;
  const int swz = (bid & 7) * (nwg >> 3) + (bid >> 3);
  const int gxm = (1 << lgx) - 1;
  const int bx  = swz & gxm;
  const int by  = swz >> lgx;
  const int bn0 = bx * 64, bm0 = by * 64;

  const bf16_t* Ag = A + (size_t)bm0 * K;
  const bf16_t* Bg = B + (size_t)bn0 * K;

  f32x4 acc[2][2] = {};

  // stage tile kt into buffer b; chunk(row,s) holds logical slot s^(row&7)
  auto stage = [&](int b, int kt) {
    const int k0 = kt * 64;
#pragma unroll
    for (int r = 0; r < 2; ++r) {           // A: 64*8=512 chunks, 2 rounds
      int ch  = t + r * 256;
      int row = ch >> 3, s = ch & 7;
      int sl  = s ^ (row & 7);
      gload_lds16(&As[b][ch * 8], Ag + (size_t)row * K + k0 + sl * 8);
    }
#pragma unroll
    for (int r = 0; r < 2; ++r) {           // B: 2 rounds
      int ch  = t + r * 256;
      int row = ch >> 3, s = ch & 7;
      int sl  = s ^ (row & 7);
      gload_lds16(&Bs[b][ch * 8], Bg + (size_t)row * K + k0 + sl * 8);
    }
  };

  const int nt = K >> 6;                    // 8 or 16
  stage(0, 0); stage(1, 1); stage(2, 2);    // depth-2 prologue (12 loads)

  const int ro = lane & 15;
  const int ks = lane >> 4;

  for (int tt = 0; tt < nt; ++tt) {
    // counted wait: retire tile tt's 4 loads; keep tt+1/tt+2 in flight
    const int rem = nt - 1 - tt;
    if (rem >= 2)      asm volatile("s_waitcnt vmcnt(8)" ::: "memory");
    else if (rem == 1) asm volatile("s_waitcnt vmcnt(4)" ::: "memory");
    else               asm volatile("s_waitcnt vmcnt(0)" ::: "memory");
    __builtin_amdgcn_s_barrier();           // buf (tt-1)&3 readers all done
    asm volatile("" ::: "memory");

    if (tt + 3 < nt) stage((tt + 3) & 3, tt + 3);   // into freed buffer

    const int c = tt & 3;
#pragma unroll
    for (int kk = 0; kk < 2; ++kk) {
      short8 af[2], bfr[2];
      const int slot = kk * 4 + ks;
#pragma unroll
      for (int mi = 0; mi < 2; ++mi) {
        int row = wm * 32 + mi * 16 + ro;
        int ch  = row * 8 + (slot ^ (row & 7));
        af[mi]  = *(const short8*)&As[c][ch * 8];
      }
#pragma unroll
      for (int ni = 0; ni < 2; ++ni) {
        int row = wn * 32 + ni * 16 + ro;
        int ch  = row * 8 + (slot ^ (row & 7));
        bfr[ni] = *(const short8*)&Bs[c][ch * 8];
      }
      __builtin_amdgcn_s_setprio(1);
#pragma unroll
      for (int mi = 0; mi < 2; ++mi)
#pragma unroll
        for (int ni = 0; ni < 2; ++ni)
          acc[mi][ni] = __builtin_amdgcn_mfma_f32_16x16x32_bf16(
              af[mi], bfr[ni], acc[mi][ni], 0, 0, 0);
      __builtin_amdgcn_s_setprio(0);
    }
  }

  // ---- epilogue -----------------------------------------------------------
  const int rb = bm0 + wm * 32;
  const int cb = bn0 + wn * 32;
#pragma unroll
  for (int mi = 0; mi < 2; ++mi) {
#pragma unroll
    for (int ni = 0; ni < 2; ++ni) {
      const int col = cb + ni * 16 + ro;
      const float bv = bias[col];
#pragma unroll
      for (int r = 0; r < 4; ++r) {
        const int row = rb + mi * 16 + (lane >> 4) * 4 + r;
        const size_t idx = (size_t)row * N + col;
        float v = acc[mi][ni][r] + bv;
        if (MODE == 0) {
          obf[idx] = __float2bfloat16(fmaxf(v, 0.f));
        } else {
          if (MODE == 1) kout[idx] = __float2bfloat16(v);
          float z = y_in[idx] + ccur * v;
          if (kp0) z += c0 * __bfloat162float(kp0[idx]);
          if (kp1) z += c1 * __bfloat162float(kp1[idx]);
          if (kp2) z += c2 * __bfloat162float(kp2[idx]);
          if (kp3) z += c3 * __bfloat162float(kp3[idx]);
          if (MODE == 2) yf_out[idx] = z;
          obf[idx] = __float2bfloat16(z);
        }
      }
    }
  }
}

#define GEMM_ARGS                                                           \
    const bf16_t* A, const bf16_t* B, const float* bias, bf16_t* obf,       \
    bf16_t* kout, float* yf_out, const float* y_in,                         \
    const bf16_t* kp0, const bf16_t* kp1, const bf16_t* kp2,                \
    const bf16_t* kp3, float c0, float c1, float c2, float c3, float ccur,  \
    int M, int N, int K, int lgx
#define GEMM_PASS A,B,bias,obf,kout,yf_out,y_in,kp0,kp1,kp2,kp3,c0,c1,c2,c3,ccur,M,N,K,lgx

extern "C" __global__ void __launch_bounds__(256, 2) g12relu(GEMM_ARGS) {
  gemm_core<0>(GEMM_PASS);
}
extern "C" __global__ void __launch_bounds__(256, 2) g3kcomb(GEMM_ARGS) {
  gemm_core<1>(GEMM_PASS);
}
extern "C" __global__ void __launch_bounds__(256, 2) g3ycomb(GEMM_ARGS) {
  gemm_core<2>(GEMM_PASS);
}

// ---------------------------------------------------------------------------
// single fused init: weights f32->bf16, y=x, yb=bf16(x)
// ---------------------------------------------------------------------------
extern "C" __global__ void init_all(const float* __restrict__ x,
                         const float* __restrict__ W1,
                         const float* __restrict__ W2,
                         const float* __restrict__ W3,
                         bf16_t* __restrict__ W1b, bf16_t* __restrict__ W2b,
                         bf16_t* __restrict__ W3b,
                         float* __restrict__ y, bf16_t* __restrict__ yb,
                         int n1, int n2, int n3, int ny)
{
  const int gt = blockIdx.x * blockDim.x + threadIdx.x;
  const int gs = gridDim.x * blockDim.x;
  auto cvt4 = [&](const float* in, bf16_t* outp, int n) {
    for (int i = gt * 4; i < n; i += gs * 4) {
      float4 v = *(const float4*)(in + i);
      bf16_t o[4] = {__float2bfloat16(v.x), __float2bfloat16(v.y),
                     __float2bfloat16(v.z), __float2bfloat16(v.w)};
      *(uint64_t*)(outp + i) = *(uint64_t*)o;
    }
  };
  cvt4(W1, W1b, n1);
  cvt4(W2, W2b, n2);
  cvt4(W3, W3b, n3);
  for (int i = gt * 4; i < ny; i += gs * 4) {
    float4 v = *(const float4*)(x + i);
    *(float4*)(y + i) = v;
    bf16_t o[4] = {__float2bfloat16(v.x), __float2bfloat16(v.y),
                   __float2bfloat16(v.z), __float2bfloat16(v.w)};
    *(uint64_t*)(yb + i) = *(uint64_t*)o;
  }
}

// ---------------------------------------------------------------------------
extern "C" void kernel_launch(void* const* d_in, const int* in_sizes, int n_in,
                              void* d_out, int out_size, void* d_ws, size_t ws_size,
                              hipStream_t stream)
{
  const float* x  = (const float*)d_in[0];
  const float* W1 = (const float*)d_in[1];
  const float* b1 = (const float*)d_in[2];
  const float* W2 = (const float*)d_in[3];
  const float* b2 = (const float*)d_in[4];
  const float* W3 = (const float*)d_in[5];
  const float* b3 = (const float*)d_in[6];

  const int data   = in_sizes[6];            // 512
  const int hidden = in_sizes[2];            // 1024
  const int batch  = in_sizes[0] / data;     // 4096

  char* ws = (char*)d_ws;
  size_t off = 0;
  auto alloc = [&](size_t bytes) -> void* {
    off = (off + 255) & ~(size_t)255;
    void* p = ws + off;
    off += bytes;
    return p;
  };
  const size_t nyd = (size_t)batch * data;
  const size_t nh  = (size_t)batch * hidden;

  float*  y   = (float*)alloc(nyd * 4);
  bf16_t* yb  = (bf16_t*)alloc(nyd * 2);
  bf16_t* zb  = (bf16_t*)alloc(nyd * 2);
  bf16_t* h1  = (bf16_t*)alloc(nh * 2);
  bf16_t* h2  = (bf16_t*)alloc(nh * 2);
  bf16_t* k1  = (bf16_t*)alloc(nyd * 2);
  bf16_t* k2  = (bf16_t*)alloc(nyd * 2);
  bf16_t* k3  = (bf16_t*)alloc(nyd * 2);
  bf16_t* k4  = (bf16_t*)alloc(nyd * 2);
  bf16_t* k5  = (bf16_t*)alloc(nyd * 2);
  bf16_t* W1b = (bf16_t*)alloc((size_t)hidden * data * 2);
  bf16_t* W2b = (bf16_t*)alloc((size_t)hidden * hidden * 2);
  bf16_t* W3b = (bf16_t*)alloc((size_t)data * hidden * 2);

  init_all<<<2048, 256, 0, stream>>>(x, W1, W2, W3, W1b, W2b, W3b, y, yb,
                                     hidden * data, hidden * hidden,
                                     data * hidden, (int)nyd);

  const double hh = 1.0 / 64.0;
  const float hA21 = (float)(hh * (1.0/5.0));
  const float hA31 = (float)(hh * (3.0/40.0)),    hA32 = (float)(hh * (9.0/40.0));
  const float hA41 = (float)(hh * (44.0/45.0)),   hA42 = (float)(hh * (-56.0/15.0)),
              hA43 = (float)(hh * (32.0/9.0));
  const float hA51 = (float)(hh * (19372.0/6561.0)),  hA52 = (float)(hh * (-25360.0/2187.0)),
              hA53 = (float)(hh * (64448.0/6561.0)),  hA54 = (float)(hh * (-212.0/729.0));
  const float hA61 = (float)(hh * (9017.0/3168.0)),   hA62 = (float)(hh * (-355.0/33.0)),
              hA63 = (float)(hh * (46732.0/5247.0)),  hA64 = (float)(hh * (49.0/176.0)),
              hA65 = (float)(hh * (-5103.0/18656.0));
  const float hB1 = (float)(hh * (35.0/384.0)),   hB3 = (float)(hh * (500.0/1113.0)),
              hB4 = (float)(hh * (125.0/192.0)),  hB5 = (float)(hh * (-2187.0/6784.0)),
              hB6 = (float)(hh * (11.0/84.0));

  const dim3 blk(256);
  const int gridH = (hidden / 64) * (batch / 64);   // 16*64 = 1024, lgx=4
  const int grid3 = (data / 64) * (batch / 64);     //  8*64 = 512,  lgx=3
  const int lgxH = 4, lgx3 = 3;

  auto mlp_front = [&](const bf16_t* zin) {
    g12relu<<<gridH, blk, 0, stream>>>(
        zin, W1b, b1, h1, nullptr, nullptr, nullptr,
        nullptr, nullptr, nullptr, nullptr, 0.f, 0.f, 0.f, 0.f, 0.f,
        batch, hidden, data, lgxH);
    g12relu<<<gridH, blk, 0, stream>>>(
        h1, W2b, b2, h2, nullptr, nullptr, nullptr,
        nullptr, nullptr, nullptr, nullptr, 0.f, 0.f, 0.f, 0.f, 0.f,
        batch, hidden, hidden, lgxH);
  };

  auto stage_k = [&](bf16_t* kout, const bf16_t* p0, float cc0, const bf16_t* p1, float cc1,
                     const bf16_t* p2, float cc2, const bf16_t* p3, float cc3, float ccur) {
    g3kcomb<<<grid3, blk, 0, stream>>>(
        h2, W3b, b3, zb, kout, nullptr, y,
        p0, p1, p2, p3, cc0, cc1, cc2, cc3, ccur,
        batch, data, hidden, lgx3);
  };

  for (int step = 0; step < 64; ++step) {
    mlp_front(yb);
    stage_k(k1, nullptr, 0.f, nullptr, 0.f, nullptr, 0.f, nullptr, 0.f, hA21);
    mlp_front(zb);
    stage_k(k2, k1, hA31, nullptr, 0.f, nullptr, 0.f, nullptr, 0.f, hA32);
    mlp_front(zb);
    stage_k(k3, k1, hA41, k2, hA42, nullptr, 0.f, nullptr, 0.f, hA43);
    mlp_front(zb);
    stage_k(k4, k1, hA51, k2, hA52, k3, hA53, nullptr, 0.f, hA54);
    mlp_front(zb);
    stage_k(k5, k1, hA61, k2, hA62, k3, hA63, k4, hA64, hA65);
    mlp_front(zb);
    float* yf = (step == 63) ? (float*)d_out : y;
    g3ycomb<<<grid3, blk, 0, stream>>>(
        h2, W3b, b3, yb, nullptr, yf, y,
        k1, k3, k4, k5, hB1, hB3, hB4, hB5, hB6,
        batch, data, hidden, lgx3);
  }
}

// Round 14
// 17495.459 us; speedup vs baseline: 2.9147x; 1.2975x over previous
//
#include <hip/hip_runtime.h>
#include <hip/hip_bf16.h>
#include <stdint.h>
#include <stddef.h>

using bf16_t = __hip_bfloat16;
typedef __attribute__((ext_vector_type(8))) short short8;
typedef __attribute__((ext_vector_type(4))) float f32x4;

__device__ __forceinline__ void gload_lds16(void* lds, const void* g) {
  __builtin_amdgcn_global_load_lds(
      (const __attribute__((address_space(1))) unsigned int*)g,
      (__attribute__((address_space(3))) unsigned int*)lds,
      16, 0, 0);
}

// ---------------------------------------------------------------------------
// r6-proven GEMM core: C[m][n] = sum_k A[m][k]*B[n][k], 64x64 tile, BK=64,
// 4 waves (2x2) of 32x32, 2-buffer LDS ring (32 KB -> 4 blocks/CU), depth-1
// prefetch, 1 barrier/K-step, 16B-chunk XOR swizzle via pre-swizzled source,
// XCD-bijective 1-D grid (nwg % 8 == 0).
// Epilogue MODEs (algebraic restructure: W13 = W1@W3 composes out G3+G1):
//  0 gmid: h2=relu(acc+bias)->obf;  if(aux) hsum accumulate (bf16 RMW)
//  1 gvst: vout=bf16(acc); u=yw1[idx] + ccur*acc + sum c_j*p_j[idx]
//          + bias[col] (bias=b1+sigma*c13); obf=bf16(relu(u))
//  2 gyw1: aux[idx]=bf16(acc) (=yW1); obf=bf16(relu(acc+bias))
//  3 gw13: obf=bf16(acc)   (builds W13)
//  4 gyup: z=y_in+acc+ccur*bias[col]; yf_out=z (fp32); obf=bf16(z)
// ---------------------------------------------------------------------------
template<int MODE>
__device__ __forceinline__ void gemm_core(
    const bf16_t* __restrict__ A, const bf16_t* __restrict__ B,
    const float* __restrict__ bias,
    bf16_t* __restrict__ obf,
    bf16_t* __restrict__ aux,          // M0: hsumb  M1: yw1b(rd)  M2: yw1b(wr)
    bf16_t* __restrict__ vout,         // M1: v_{s-1} store
    float* __restrict__ yf_out,        // M4: fp32 y / d_out
    const float* __restrict__ y_in,    // M4
    const bf16_t* __restrict__ p0, const bf16_t* __restrict__ p1,
    const bf16_t* __restrict__ p2, const bf16_t* __restrict__ p3,
    float c0, float c1, float c2, float c3, float ccur, int hinit,
    int M, int N, int K, int lgx)
{
  __shared__ __align__(16) bf16_t As[2][64 * 64];
  __shared__ __align__(16) bf16_t Bs[2][64 * 64];

  const int t    = threadIdx.x;
  const int lane = t & 63;
  const int wid  = t >> 6;
  const int wm   = wid >> 1;
  const int wn   = wid & 1;

  const int nwg = gridDim.x, bid = blockIdx.x;
  const int swz = (bid & 7) * (nwg >> 3) + (bid >> 3);
  const int gxm = (1 << lgx) - 1;
  const int bx  = swz & gxm;
  const int by  = swz >> lgx;
  const int bn0 = bx * 64, bm0 = by * 64;

  const bf16_t* Ag = A + (size_t)bm0 * K;
  const bf16_t* Bg = B + (size_t)bn0 * K;

  f32x4 acc[2][2] = {};

  auto stage = [&](int b, int kt) {
    const int k0 = kt * 64;
#pragma unroll
    for (int r = 0; r < 2; ++r) {
      int ch  = t + r * 256;
      int row = ch >> 3, s = ch & 7;
      int sl  = s ^ (row & 7);
      gload_lds16(&As[b][ch * 8], Ag + (size_t)row * K + k0 + sl * 8);
    }
#pragma unroll
    for (int r = 0; r < 2; ++r) {
      int ch  = t + r * 256;
      int row = ch >> 3, s = ch & 7;
      int sl  = s ^ (row & 7);
      gload_lds16(&Bs[b][ch * 8], Bg + (size_t)row * K + k0 + sl * 8);
    }
  };

  const int nt = K >> 6;
  stage(0, 0);

  const int ro = lane & 15;
  const int ks = lane >> 4;

  for (int tt = 0; tt < nt; ++tt) {
    const int c = tt & 1;
    asm volatile("s_waitcnt vmcnt(0)" ::: "memory");
    __builtin_amdgcn_s_barrier();
    asm volatile("" ::: "memory");
    if (tt + 1 < nt) stage(c ^ 1, tt + 1);

#pragma unroll
    for (int kk = 0; kk < 2; ++kk) {
      short8 af[2], bfr[2];
      const int slot = kk * 4 + ks;
#pragma unroll
      for (int mi = 0; mi < 2; ++mi) {
        int row = wm * 32 + mi * 16 + ro;
        int ch  = row * 8 + (slot ^ (row & 7));
        af[mi]  = *(const short8*)&As[c][ch * 8];
      }
#pragma unroll
      for (int ni = 0; ni < 2; ++ni) {
        int row = wn * 32 + ni * 16 + ro;
        int ch  = row * 8 + (slot ^ (row & 7));
        bfr[ni] = *(const short8*)&Bs[c][ch * 8];
      }
      __builtin_amdgcn_s_setprio(1);
#pragma unroll
      for (int mi = 0; mi < 2; ++mi)
#pragma unroll
        for (int ni = 0; ni < 2; ++ni)
          acc[mi][ni] = __builtin_amdgcn_mfma_f32_16x16x32_bf16(
              af[mi], bfr[ni], acc[mi][ni], 0, 0, 0);
      __builtin_amdgcn_s_setprio(0);
    }
  }

  // ---- epilogue -----------------------------------------------------------
  const int rb = bm0 + wm * 32;
  const int cb = bn0 + wn * 32;
#pragma unroll
  for (int mi = 0; mi < 2; ++mi) {
#pragma unroll
    for (int ni = 0; ni < 2; ++ni) {
      const int col = cb + ni * 16 + ro;
      const float bv = bias ? bias[col] : 0.f;
#pragma unroll
      for (int r = 0; r < 4; ++r) {
        const int row = rb + mi * 16 + (lane >> 4) * 4 + r;
        const size_t idx = (size_t)row * N + col;
        const float a = acc[mi][ni][r];
        if (MODE == 0) {
          float v = fmaxf(a + bv, 0.f);
          obf[idx] = __float2bfloat16(v);
          if (aux) {
            float hs = ccur * v + (hinit ? 0.f : __bfloat162float(aux[idx]));
            aux[idx] = __float2bfloat16(hs);
          }
        } else if (MODE == 1) {
          vout[idx] = __float2bfloat16(a);
          float u = __bfloat162float(aux[idx]) + ccur * a + bv;
          if (p0) u += c0 * __bfloat162float(p0[idx]);
          if (p1) u += c1 * __bfloat162float(p1[idx]);
          if (p2) u += c2 * __bfloat162float(p2[idx]);
          if (p3) u += c3 * __bfloat162float(p3[idx]);
          obf[idx] = __float2bfloat16(fmaxf(u, 0.f));
        } else if (MODE == 2) {
          aux[idx] = __float2bfloat16(a);
          obf[idx] = __float2bfloat16(fmaxf(a + bv, 0.f));
        } else if (MODE == 3) {
          obf[idx] = __float2bfloat16(a);
        } else {  // MODE 4
          float z = y_in[idx] + a + ccur * bv;
          yf_out[idx] = z;
          obf[idx] = __float2bfloat16(z);
        }
      }
    }
  }
}

#define GARGS                                                               \
    const bf16_t* A, const bf16_t* B, const float* bias, bf16_t* obf,       \
    bf16_t* aux, bf16_t* vout, float* yf_out, const float* y_in,            \
    const bf16_t* p0, const bf16_t* p1, const bf16_t* p2, const bf16_t* p3, \
    float c0, float c1, float c2, float c3, float ccur, int hinit,          \
    int M, int N, int K, int lgx
#define GPASS A,B,bias,obf,aux,vout,yf_out,y_in,p0,p1,p2,p3,c0,c1,c2,c3,ccur,hinit,M,N,K,lgx

extern "C" __global__ void __launch_bounds__(256, 4) gmid(GARGS) { gemm_core<0>(GPASS); }
extern "C" __global__ void __launch_bounds__(256, 4) gvst(GARGS) { gemm_core<1>(GPASS); }
extern "C" __global__ void __launch_bounds__(256, 4) gyw1(GARGS) { gemm_core<2>(GPASS); }
extern "C" __global__ void __launch_bounds__(256, 4) gw13(GARGS) { gemm_core<3>(GPASS); }
extern "C" __global__ void __launch_bounds__(256, 4) gyup(GARGS) { gemm_core<4>(GPASS); }

// ---------------------------------------------------------------------------
// init: W1/W2/W3 -> bf16; W3T (transposed bf16, for W13 build); y=x; yb;
// c13[c] = sum_d b3[d]*W1[c][d]; biasS_s = b1 + sigma_s*c13 (s=2..6)
// ---------------------------------------------------------------------------
extern "C" __global__ void init_all(
    const float* __restrict__ x,
    const float* __restrict__ W1, const float* __restrict__ W2,
    const float* __restrict__ W3,
    const float* __restrict__ b1, const float* __restrict__ b3,
    bf16_t* __restrict__ W1b, bf16_t* __restrict__ W2b,
    bf16_t* __restrict__ W3b, bf16_t* __restrict__ W3Tb,
    float* __restrict__ y, bf16_t* __restrict__ yb,
    float* __restrict__ bS2, float* __restrict__ bS3, float* __restrict__ bS4,
    float* __restrict__ bS5, float* __restrict__ bS6,
    float s2, float s3, float s4, float s5, float s6)
{
  const int gt = blockIdx.x * blockDim.x + threadIdx.x;
  const int gs = gridDim.x * blockDim.x;
  auto cvt4 = [&](const float* in, bf16_t* outp, int n) {
    for (int i = gt * 4; i < n; i += gs * 4) {
      float4 v = *(const float4*)(in + i);
      bf16_t o[4] = {__float2bfloat16(v.x), __float2bfloat16(v.y),
                     __float2bfloat16(v.z), __float2bfloat16(v.w)};
      *(uint64_t*)(outp + i) = *(uint64_t*)o;
    }
  };
  cvt4(W1, W1b, 1024 * 512);
  cvt4(W2, W2b, 1024 * 1024);
  cvt4(W3, W3b, 512 * 1024);
  for (int i = gt; i < 512 * 1024; i += gs) {      // W3T[j][d] = W3[d][j]
    int d = i >> 10, j = i & 1023;
    W3Tb[(size_t)j * 512 + d] = __float2bfloat16(W3[i]);
  }
  for (int i = gt * 4; i < 4096 * 512; i += gs * 4) {
    float4 v = *(const float4*)(x + i);
    *(float4*)(y + i) = v;
    bf16_t o[4] = {__float2bfloat16(v.x), __float2bfloat16(v.y),
                   __float2bfloat16(v.z), __float2bfloat16(v.w)};
    *(uint64_t*)(yb + i) = *(uint64_t*)o;
  }
  if (gt < 1024) {                                  // c13 + stage biases
    float c13 = 0.f;
    const float* wr = W1 + (size_t)gt * 512;
    for (int d = 0; d < 512; ++d) c13 += b3[d] * wr[d];
    const float bb = b1[gt];
    bS2[gt] = bb + s2 * c13;
    bS3[gt] = bb + s3 * c13;
    bS4[gt] = bb + s4 * c13;
    bS5[gt] = bb + s5 * c13;
    bS6[gt] = bb + s6 * c13;
  }
}

// ---------------------------------------------------------------------------
extern "C" void kernel_launch(void* const* d_in, const int* in_sizes, int n_in,
                              void* d_out, int out_size, void* d_ws, size_t ws_size,
                              hipStream_t stream)
{
  const float* x  = (const float*)d_in[0];
  const float* W1 = (const float*)d_in[1];
  const float* b1 = (const float*)d_in[2];
  const float* W2 = (const float*)d_in[3];
  const float* b2 = (const float*)d_in[4];
  const float* W3 = (const float*)d_in[5];
  const float* b3 = (const float*)d_in[6];

  constexpr int BATCH = 4096, DATA = 512, HID = 1024;

  char* ws = (char*)d_ws;
  size_t off = 0;
  auto alloc = [&](size_t bytes) -> void* {
    off = (off + 255) & ~(size_t)255;
    void* p = ws + off;
    off += bytes;
    return p;
  };
  const size_t nyd = (size_t)BATCH * DATA;
  const size_t nh  = (size_t)BATCH * HID;

  float*  y    = (float*)alloc(nyd * 4);
  bf16_t* yb   = (bf16_t*)alloc(nyd * 2);
  bf16_t* h1b  = (bf16_t*)alloc(nh * 2);
  bf16_t* h2b  = (bf16_t*)alloc(nh * 2);
  bf16_t* yw1b = (bf16_t*)alloc(nh * 2);
  bf16_t* hsumb= (bf16_t*)alloc(nh * 2);
  bf16_t* v1   = (bf16_t*)alloc(nh * 2);
  bf16_t* v2   = (bf16_t*)alloc(nh * 2);
  bf16_t* v3   = (bf16_t*)alloc(nh * 2);
  bf16_t* v4   = (bf16_t*)alloc(nh * 2);
  bf16_t* v5   = (bf16_t*)alloc(nh * 2);
  bf16_t* W1b  = (bf16_t*)alloc((size_t)HID * DATA * 2);
  bf16_t* W2b  = (bf16_t*)alloc((size_t)HID * HID * 2);
  bf16_t* W3b  = (bf16_t*)alloc((size_t)DATA * HID * 2);
  bf16_t* W3Tb = (bf16_t*)alloc((size_t)HID * DATA * 2);
  bf16_t* W13b = (bf16_t*)alloc((size_t)HID * HID * 2);
  float*  bS2  = (float*)alloc(HID * 4);
  float*  bS3  = (float*)alloc(HID * 4);
  float*  bS4  = (float*)alloc(HID * 4);
  float*  bS5  = (float*)alloc(HID * 4);
  float*  bS6  = (float*)alloc(HID * 4);

  const double hh = 1.0 / 64.0;
  const float hA21 = (float)(hh * (1.0/5.0));
  const float hA31 = (float)(hh * (3.0/40.0)),    hA32 = (float)(hh * (9.0/40.0));
  const float hA41 = (float)(hh * (44.0/45.0)),   hA42 = (float)(hh * (-56.0/15.0)),
              hA43 = (float)(hh * (32.0/9.0));
  const float hA51 = (float)(hh * (19372.0/6561.0)),  hA52 = (float)(hh * (-25360.0/2187.0)),
              hA53 = (float)(hh * (64448.0/6561.0)),  hA54 = (float)(hh * (-212.0/729.0));
  const float hA61 = (float)(hh * (9017.0/3168.0)),   hA62 = (float)(hh * (-355.0/33.0)),
              hA63 = (float)(hh * (46732.0/5247.0)),  hA64 = (float)(hh * (49.0/176.0)),
              hA65 = (float)(hh * (-5103.0/18656.0));
  const float hB1 = (float)(hh * (35.0/384.0)),   hB3 = (float)(hh * (500.0/1113.0)),
              hB4 = (float)(hh * (125.0/192.0)),  hB5 = (float)(hh * (-2187.0/6784.0)),
              hB6 = (float)(hh * (11.0/84.0));
  const float s2 = hA21, s3 = hA31 + hA32, s4 = hA41 + hA42 + hA43,
              s5 = hA51 + hA52 + hA53 + hA54,
              s6 = hA61 + hA62 + hA63 + hA64 + hA65;

  init_all<<<2048, 256, 0, stream>>>(x, W1, W2, W3, b1, b3,
                                     W1b, W2b, W3b, W3Tb, y, yb,
                                     bS2, bS3, bS4, bS5, bS6,
                                     s2, s3, s4, s5, s6);

  const dim3 blk(256);
  const int gridN = (HID / 64) * (BATCH / 64);    // 1024, lgx=4
  const int gridY = (DATA / 64) * (BATCH / 64);   // 512,  lgx=3
  const int gridW = (HID / 64) * (HID / 64);      // 256,  lgx=4

  // W13 = W1 @ W3  (C[i][j] = sum_d W1b[i][d] * W3Tb[j][d])
  gw13<<<gridW, blk, 0, stream>>>(
      W1b, W3Tb, nullptr, W13b, nullptr, nullptr, nullptr, nullptr,
      nullptr, nullptr, nullptr, nullptr, 0.f, 0.f, 0.f, 0.f, 0.f, 0,
      HID, HID, DATA, 4);

  auto G2 = [&](bf16_t* hs, float coef, int hinit) {
    gmid<<<gridN, blk, 0, stream>>>(
        h1b, W2b, b2, h2b, hs, nullptr, nullptr, nullptr,
        nullptr, nullptr, nullptr, nullptr,
        0.f, 0.f, 0.f, 0.f, coef, hinit, BATCH, HID, HID, 4);
  };
  auto V = [&](bf16_t* vo, const float* bS, float ccur,
               const bf16_t* q0, float cc0, const bf16_t* q1, float cc1,
               const bf16_t* q2, float cc2, const bf16_t* q3, float cc3) {
    gvst<<<gridN, blk, 0, stream>>>(
        h2b, W13b, bS, h1b, yw1b, vo, nullptr, nullptr,
        q0, q1, q2, q3, cc0, cc1, cc2, cc3, ccur, 0, BATCH, HID, HID, 4);
  };

  for (int step = 0; step < 64; ++step) {
    // stage 1: yW1 GEMM (K=512), h1_1 = relu(yW1 + b1), store yw1b
    gyw1<<<gridN, blk, 0, stream>>>(
        yb, W1b, b1, h1b, yw1b, nullptr, nullptr, nullptr,
        nullptr, nullptr, nullptr, nullptr,
        0.f, 0.f, 0.f, 0.f, 0.f, 0, BATCH, HID, DATA, 4);
    G2(hsumb, hB1, 1);                                   // h2_1, hsum init
    // stages 2..6: v_{s-1} GEMM + fused h1_s epilogue, then G2
    V(v1, bS2, hA21, nullptr,0,nullptr,0,nullptr,0,nullptr,0);
    G2(nullptr, 0.f, 0);                                 // h2_2 (B2 = 0)
    V(v2, bS3, hA32, v1,hA31, nullptr,0,nullptr,0,nullptr,0);
    G2(hsumb, hB3, 0);                                   // h2_3
    V(v3, bS4, hA43, v1,hA41, v2,hA42, nullptr,0,nullptr,0);
    G2(hsumb, hB4, 0);                                   // h2_4
    V(v4, bS5, hA54, v1,hA51, v2,hA52, v3,hA53, nullptr,0);
    G2(hsumb, hB5, 0);                                   // h2_5
    V(v5, bS6, hA65, v1,hA61, v2,hA62, v3,hA63, v4,hA64);
    G2(hsumb, hB6, 0);                                   // h2_6, hsum final
    // y_{n+1} = y + hsum@W3^T + h*b3   (sum B_j = 1)
    float* yf = (step == 63) ? (float*)d_out : y;
    gyup<<<gridY, blk, 0, stream>>>(
        hsumb, W3b, b3, yb, nullptr, nullptr, yf, y,
        nullptr, nullptr, nullptr, nullptr,
        0.f, 0.f, 0.f, 0.f, (float)hh, 0, BATCH, DATA, HID, 3);
  }
}